// Round 1
// baseline (360.874 us; speedup 1.0000x reference)
//
#include <hip/hip_runtime.h>

// LSTM_71382356459716: B=16384 rows, T=28, IN=28, HID=64 (gates 4H=256), OUT=10.
// Fused single-kernel fp32 baseline: one block owns 64 batch rows for all 28
// timesteps (recurrence is batch-independent). Weights staged once in LDS,
// h/c never leave the CU. fp32 VALU roofline ~137us; this establishes a
// correct baseline + measured absmax headroom before the bf16-MFMA rewrite.

namespace {
constexpr int B_TOT   = 16384;
constexpr int T_STEPS = 28;
constexpr int IN_DIM  = 28;
constexpr int HID     = 64;
constexpr int G4      = 256;   // 4*HID, gate order i,f,g,o
constexpr int OUT_DIM = 10;
constexpr int ROWS    = 64;    // batch rows per block
constexpr int THREADS = 512;   // 8 waves
constexpr int RPAD    = 68;    // padded row stride for xs/hs (keeps float4 16B-aligned)
constexpr int XROW    = T_STEPS * IN_DIM;  // 784 floats per batch row of x
}

__device__ __forceinline__ float fast_sigmoid(float v) {
  return __builtin_amdgcn_rcpf(1.0f + __expf(-v));
}
__device__ __forceinline__ float fast_tanh(float v) {
  // tanh(v) = 2*sigmoid(2v) - 1 ; saturates correctly for |v| large (rcp(inf)=0)
  return 2.0f * __builtin_amdgcn_rcpf(1.0f + __expf(-2.0f * v)) - 1.0f;
}

// Gate column permutation: global gate g = ty*64 + j (ty: 0=i,1=f,2=g,3=o).
// Stored interleaved so one float4 = (i_j, f_j, i_{j+1}, f_{j+1}) and the
// second half float4 = (g_j, o_j, g_{j+1}, o_{j+1}) -> two stride-16B
// conflict-free ds_read_b128 per k per thread.
__device__ __forceinline__ int gate_pos(int g) {
  int ty = g >> 6, j = g & 63;
  return (ty < 2) ? (2 * j + ty) : (128 + 2 * j + (ty - 2));
}

__global__ __launch_bounds__(THREADS, 2)
void lstm_fused(const float* __restrict__ x, const float* __restrict__ W_ih,
                const float* __restrict__ W_hh, const float* __restrict__ b_ih,
                const float* __restrict__ b_hh, const float* __restrict__ W_fc,
                const float* __restrict__ b_fc, float* __restrict__ out) {
  __shared__ float Wt[IN_DIM + HID][G4];  // 92*256*4 = 94208 B, [k][permuted gate]
  __shared__ float biasP[G4];             // b_ih + b_hh, permuted
  __shared__ float xs[IN_DIM][RPAD];      // x tile, [k][row], 7616 B
  __shared__ float hs[HID][RPAD];         // h tile, [k][row], 17408 B

  const int tid = threadIdx.x;
  const int b0  = blockIdx.x * ROWS;

  // ---- stage weights into LDS (once per block; ~23.5MB total chip-wide, L2-served) ----
  for (int idx = tid; idx < G4 * IN_DIM; idx += THREADS) {
    int g = idx / IN_DIM;
    int k = idx - g * IN_DIM;
    Wt[k][gate_pos(g)] = W_ih[idx];
  }
  for (int idx = tid; idx < G4 * HID; idx += THREADS) {
    int g = idx >> 6;
    int k = idx & 63;
    Wt[IN_DIM + k][gate_pos(g)] = W_hh[idx];
  }
  if (tid < G4) biasP[gate_pos(tid)] = b_ih[tid] + b_hh[tid];
  for (int idx = tid; idx < HID * RPAD; idx += THREADS) (&hs[0][0])[idx] = 0.0f;
  // x tile for t=0
  for (int idx = tid; idx < IN_DIM * ROWS; idx += THREADS) {
    int k = idx >> 6, r = idx & 63;
    xs[k][r] = x[(b0 + r) * XROW + k];
  }
  __syncthreads();

  // thread tile: 4 rows x 2 hidden units (all 4 gate types local -> no exchange)
  const int gg = tid & 31;   // gate-group 0..31
  const int rg = tid >> 5;   // row-group 0..15
  const int jb = gg * 4;     // column base in interleaved W layout
  const int j0 = gg * 2;     // hidden-unit base
  const int r0 = rg * 4;     // row base

  float c_state[4][2] = {{0.f, 0.f}, {0.f, 0.f}, {0.f, 0.f}, {0.f, 0.f}};
  float acc[4][8];

  for (int t = 0; t < T_STEPS; ++t) {
    // prefetch next timestep's x tile into registers; latency hides under GEMM
    float rx[4];
    const bool hasNext = (t + 1 < T_STEPS);
    if (hasNext) {
#pragma unroll
      for (int q = 0; q < 4; ++q) {
        int idx = tid + q * THREADS;
        if (idx < IN_DIM * ROWS) {
          int k = idx >> 6, r = idx & 63;
          rx[q] = x[(b0 + r) * XROW + (t + 1) * IN_DIM + k];
        }
      }
    }

    // init accumulators with (b_ih + b_hh)
    float4 bA = *(const float4*)&biasP[jb];
    float4 bB = *(const float4*)&biasP[128 + jb];
#pragma unroll
    for (int r = 0; r < 4; ++r) {
      acc[r][0] = bA.x; acc[r][1] = bA.y; acc[r][2] = bA.z; acc[r][3] = bA.w;
      acc[r][4] = bB.x; acc[r][5] = bB.y; acc[r][6] = bB.z; acc[r][7] = bB.w;
    }

    // gates += x_t * W_ih^T
#pragma unroll 4
    for (int k = 0; k < IN_DIM; ++k) {
      float4 xv = *(const float4*)&xs[k][r0];
      float4 wA = *(const float4*)&Wt[k][jb];
      float4 wB = *(const float4*)&Wt[k][128 + jb];
      float xr[4] = {xv.x, xv.y, xv.z, xv.w};
#pragma unroll
      for (int r = 0; r < 4; ++r) {
        acc[r][0] += xr[r] * wA.x; acc[r][1] += xr[r] * wA.y;
        acc[r][2] += xr[r] * wA.z; acc[r][3] += xr[r] * wA.w;
        acc[r][4] += xr[r] * wB.x; acc[r][5] += xr[r] * wB.y;
        acc[r][6] += xr[r] * wB.z; acc[r][7] += xr[r] * wB.w;
      }
    }
    // gates += h_{t-1} * W_hh^T
#pragma unroll 4
    for (int k = 0; k < HID; ++k) {
      float4 hv = *(const float4*)&hs[k][r0];
      float4 wA = *(const float4*)&Wt[IN_DIM + k][jb];
      float4 wB = *(const float4*)&Wt[IN_DIM + k][128 + jb];
      float hr[4] = {hv.x, hv.y, hv.z, hv.w};
#pragma unroll
      for (int r = 0; r < 4; ++r) {
        acc[r][0] += hr[r] * wA.x; acc[r][1] += hr[r] * wA.y;
        acc[r][2] += hr[r] * wA.z; acc[r][3] += hr[r] * wA.w;
        acc[r][4] += hr[r] * wB.x; acc[r][5] += hr[r] * wB.y;
        acc[r][6] += hr[r] * wB.z; acc[r][7] += hr[r] * wB.w;
      }
    }

    __syncthreads();  // all reads of xs/hs for step t complete

    if (hasNext) {
#pragma unroll
      for (int q = 0; q < 4; ++q) {
        int idx = tid + q * THREADS;
        if (idx < IN_DIM * ROWS) {
          int k = idx >> 6, r = idx & 63;
          xs[k][r] = rx[q];
        }
      }
    }

    // activations + state update; h written transposed for next step's reads
#pragma unroll
    for (int r = 0; r < 4; ++r) {
#pragma unroll
      for (int jj = 0; jj < 2; ++jj) {
        float iv = fast_sigmoid(acc[r][2 * jj + 0]);
        float fv = fast_sigmoid(acc[r][2 * jj + 1]);
        float gv = fast_tanh(acc[r][4 + 2 * jj + 0]);
        float ov = fast_sigmoid(acc[r][4 + 2 * jj + 1]);
        float cn = fv * c_state[r][jj] + iv * gv;
        c_state[r][jj] = cn;
        hs[j0 + jj][r0 + r] = ov * fast_tanh(cn);
      }
    }
    __syncthreads();  // hs (and xs) ready for step t+1
  }

  // ---- FC epilogue: out[b][o] = h_last[b] . W_fc[o] + b_fc[o] ----
  float* wfc = &xs[0][0];  // xs is free now (1904 floats >= 640)
  for (int idx = tid; idx < OUT_DIM * HID; idx += THREADS) wfc[idx] = W_fc[idx];
  __syncthreads();
  for (int idx = tid; idx < ROWS * OUT_DIM; idx += THREADS) {
    int o = idx >> 6;   // 0..9
    int r = idx & 63;
    float s = b_fc[o];
#pragma unroll
    for (int j = 0; j < HID; ++j) s += hs[j][r] * wfc[o * HID + j];
    out[(b0 + r) * OUT_DIM + o] = s;
  }
}

extern "C" void kernel_launch(void* const* d_in, const int* in_sizes, int n_in,
                              void* d_out, int out_size, void* d_ws, size_t ws_size,
                              hipStream_t stream) {
  const float* x    = (const float*)d_in[0];
  const float* W_ih = (const float*)d_in[1];
  const float* W_hh = (const float*)d_in[2];
  const float* b_ih = (const float*)d_in[3];
  const float* b_hh = (const float*)d_in[4];
  const float* W_fc = (const float*)d_in[5];
  const float* b_fc = (const float*)d_in[6];
  float* out = (float*)d_out;

  dim3 grid(B_TOT / ROWS);   // 256 blocks, 1 per CU (LDS-limited)
  dim3 block(THREADS);
  lstm_fused<<<grid, block, 0, stream>>>(x, W_ih, W_hh, b_ih, b_hh, W_fc, b_fc, out);
}

// Round 2
// 134.087 us; speedup vs baseline: 2.6913x; 2.6913x over previous
//
#include <hip/hip_runtime.h>

// LSTM_71382356459716 R1: MFMA rewrite, weight-stationary in registers.
// gates^T = Wperm(256x96) * [x_t ; h_{t-1}]^T(96x32rows) via mfma_f32_16x16x32_bf16.
// Gate rows permuted unit-major (m = unit*4 + type) so each C-tile reg tuple
// (reg0..3) = (i,f,g,o) of ONE (unit,row) in ONE lane -> activations + c/h
// update fully lane-local. W lives in VGPRs for all 28 steps (zero LDS traffic
// for the big operand); only x||h (96x32 bf16, double-buffered) cycles through
// LDS -> 6 ds_read_b128 + 12 MFMA + 4 ds_write_b16 per wave per step, 1 barrier.

namespace {
constexpr int B_TOT   = 16384;
constexpr int T_STEPS = 28;
constexpr int IN_DIM  = 28;
constexpr int HID     = 64;
constexpr int OUT_DIM = 10;
constexpr int ROWS    = 32;    // batch rows per block -> 512 blocks, 2 blocks/CU
constexpr int THREADS = 512;   // 8 waves
constexpr int KPAD    = 104;   // bf16 elems per LDS row (208B stride = 13*16B, odd)
constexpr int XROW    = T_STEPS * IN_DIM;  // 784 floats per batch row of x
}

typedef __attribute__((ext_vector_type(8))) short short8v;   // 8 bf16 (4 VGPRs)
typedef __attribute__((ext_vector_type(4))) short short4v;
typedef __attribute__((ext_vector_type(4))) float float4v;

__device__ __forceinline__ short f2bf(float f) {
  union { float f; unsigned u; } v; v.f = f;
  unsigned r = v.u + 0x7FFFu + ((v.u >> 16) & 1u);   // RNE
  return (short)(r >> 16);
}
__device__ __forceinline__ float bf2f(short s) {
  union { unsigned u; float f; } v; v.u = ((unsigned)(unsigned short)s) << 16;
  return v.f;
}
__device__ __forceinline__ float sigf(float v) {
  return __builtin_amdgcn_rcpf(1.0f + __expf(-v));
}
__device__ __forceinline__ float tanh_f(float v) {
  return 2.0f * __builtin_amdgcn_rcpf(1.0f + __expf(-2.0f * v)) - 1.0f;
}

__global__ __launch_bounds__(THREADS, 4)
void lstm_mfma(const float* __restrict__ x, const float* __restrict__ W_ih,
               const float* __restrict__ W_hh, const float* __restrict__ b_ih,
               const float* __restrict__ b_hh, const float* __restrict__ W_fc,
               const float* __restrict__ b_fc, float* __restrict__ out) {
  // [buf][row][k] bf16; k 0..27 = x_t, 28..31 = 0, 32..95 = h. 13312 B total.
  __shared__ short hs[2][ROWS][KPAD];

  const int tid  = threadIdx.x;
  const int lane = tid & 63;
  const int w    = tid >> 6;      // wave 0..7 -> owns units 8w..8w+7
  const int b0   = blockIdx.x * ROWS;
  const int l15  = lane & 15;
  const int q    = lane >> 4;     // 0..3

  // ---- stationary A-operand (weights), gate-permuted unit-major ------------
  // A-frag layout: lane holds A[m = 16*mt + (lane&15)][k = kc*32 + q*8 + j].
  // permuted m: unit = m>>2, type = m&3; original gate row g = type*64 + unit.
  short8v a[2][3];
  float4v bias[2];
#pragma unroll
  for (int mtl = 0; mtl < 2; ++mtl) {
    const int mt   = 2 * w + mtl;
    const int m    = 16 * mt + l15;
    const int unit = m >> 2, type = m & 3;
    const int g    = type * 64 + unit;
#pragma unroll
    for (int kc = 0; kc < 3; ++kc) {
      short8v frag;
#pragma unroll
      for (int j = 0; j < 8; ++j) {
        const int k = kc * 32 + q * 8 + j;
        float v = 0.0f;
        if (k < IN_DIM)      v = W_ih[g * IN_DIM + k];
        else if (k >= 32)    v = W_hh[g * HID + (k - 32)];
        frag[j] = f2bf(v);
      }
      a[mtl][kc] = frag;
    }
    const int ub = 4 * mt + q;    // unit owned by this lane's C regs
    float4v bv;
#pragma unroll
    for (int r = 0; r < 4; ++r) bv[r] = b_ih[r * 64 + ub] + b_hh[r * 64 + ub];
    bias[mtl] = bv;
  }

  // x staging: 32 rows * 7 float4 per step; thread tid<224 owns one float4
  const bool xldr = (tid < ROWS * 7);
  const int  xr   = tid / 7;
  const int  xc4  = tid - 7 * xr;

  // ---- init: zero both buffers (h region of buf0 + pads), stage x_0 --------
  float4 xv0 = {0.f, 0.f, 0.f, 0.f};
  if (xldr) xv0 = *(const float4*)&x[(b0 + xr) * XROW + 0 * IN_DIM + xc4 * 4];
  for (int idx = tid; idx < 2 * ROWS * KPAD; idx += THREADS)
    (&hs[0][0][0])[idx] = 0;
  __syncthreads();
  if (xldr) {
    short4v s; s[0] = f2bf(xv0.x); s[1] = f2bf(xv0.y); s[2] = f2bf(xv0.z); s[3] = f2bf(xv0.w);
    *(short4v*)&hs[0][xr][xc4 * 4] = s;
  }
  __syncthreads();

  float c_state[2][2] = {{0.f, 0.f}, {0.f, 0.f}};

  for (int t = 0; t < T_STEPS; ++t) {
    const int cur = t & 1, nxt = cur ^ 1;
    const bool hasNext = (t + 1 < T_STEPS);

    // prefetch next x tile (global latency hides under MFMA+activations)
    float4 xv = {0.f, 0.f, 0.f, 0.f};
    if (hasNext && xldr)
      xv = *(const float4*)&x[(b0 + xr) * XROW + (t + 1) * IN_DIM + xc4 * 4];

    float4v acc[2][2];
#pragma unroll
    for (int mtl = 0; mtl < 2; ++mtl)
#pragma unroll
      for (int nt = 0; nt < 2; ++nt) acc[mtl][nt] = bias[mtl];

    // B-frag: lane holds B[k = kc*32 + q*8 + j][n = 16*nt + (lane&15)]
#pragma unroll
    for (int kc = 0; kc < 3; ++kc) {
      short8v bf[2];
#pragma unroll
      for (int nt = 0; nt < 2; ++nt)
        bf[nt] = *(const short8v*)&hs[cur][16 * nt + l15][kc * 32 + q * 8];
#pragma unroll
      for (int mtl = 0; mtl < 2; ++mtl)
#pragma unroll
        for (int nt = 0; nt < 2; ++nt)
          acc[mtl][nt] = __builtin_amdgcn_mfma_f32_16x16x32_bf16(
              a[mtl][kc], bf[nt], acc[mtl][nt], 0, 0, 0);
    }

    // activations + state update (all lane-local: regs = i,f,g,o of one unit)
#pragma unroll
    for (int mtl = 0; mtl < 2; ++mtl) {
      const int u = 4 * (2 * w + mtl) + q;
#pragma unroll
      for (int nt = 0; nt < 2; ++nt) {
        float4v g4 = acc[mtl][nt];
        float iv = sigf(g4[0]);
        float fv = sigf(g4[1]);
        float gv = tanh_f(g4[2]);
        float ov = sigf(g4[3]);
        float cn = fv * c_state[mtl][nt] + iv * gv;
        c_state[mtl][nt] = cn;
        float hv = ov * tanh_f(cn);
        hs[nxt][16 * nt + l15][32 + u] = f2bf(hv);
      }
    }

    if (hasNext && xldr) {
      short4v s; s[0] = f2bf(xv.x); s[1] = f2bf(xv.y); s[2] = f2bf(xv.z); s[3] = f2bf(xv.w);
      *(short4v*)&hs[nxt][xr][xc4 * 4] = s;
    }
    __syncthreads();
  }

  // ---- FC epilogue: final h is in hs[0] (t=27 wrote nxt=0) -----------------
  if (tid < ROWS * OUT_DIM) {           // 320 outputs per block
    const int r = tid / OUT_DIM;
    const int o = tid - r * OUT_DIM;
    float s = b_fc[o];
#pragma unroll
    for (int j = 0; j < HID; ++j)
      s += bf2f(hs[0][r][32 + j]) * W_fc[o * HID + j];
    out[(b0 + r) * OUT_DIM + o] = s;
  }
}

extern "C" void kernel_launch(void* const* d_in, const int* in_sizes, int n_in,
                              void* d_out, int out_size, void* d_ws, size_t ws_size,
                              hipStream_t stream) {
  const float* x    = (const float*)d_in[0];
  const float* W_ih = (const float*)d_in[1];
  const float* W_hh = (const float*)d_in[2];
  const float* b_ih = (const float*)d_in[3];
  const float* b_hh = (const float*)d_in[4];
  const float* W_fc = (const float*)d_in[5];
  const float* b_fc = (const float*)d_in[6];
  float* out = (float*)d_out;

  dim3 grid(B_TOT / ROWS);   // 512 blocks -> 2 blocks/CU
  dim3 block(THREADS);
  lstm_mfma<<<grid, block, 0, stream>>>(x, W_ih, W_hh, b_ih, b_hh, W_fc, b_fc, out);
}